// Round 1
// baseline (12219.566 us; speedup 1.0000x reference)
//
#include <hip/hip_runtime.h>
#include <math.h>

#define Bq 8
#define Sq 256
#define Hq 768
#define FFq 3072
#define NHq 12
#define MROWS (Bq*Sq)          /* 2048 */
#define BSH (Bq*Sq*Hq)         /* 1,572,864 */
#define SCSZ (Bq*NHq*Sq*Sq)    /* 6,291,456 */

// ---------------------------------------------------------------------------
// Tiled fp32 GEMM: C = A[M,K] @ W[K,N] + bias (+resid) (+gelu)
// MODE: 0 = bias, 1 = bias+resid, 2 = bias+gelu(exact)
// TW: per-thread microtile (4 -> 64x64 block tile, 8 -> 128x128)
// grid.z batches W/bias/C by strides (QKV).
// ---------------------------------------------------------------------------
template<int MODE, int TW>
__global__ __launch_bounds__(256)
void gemm_nn(const float* __restrict__ A, const float* __restrict__ W,
             const float* __restrict__ bias, const float* __restrict__ resid,
             float* __restrict__ C, int M, int N, int K,
             long sW, long sBias, long sC)
{
  constexpr int BM = 16 * TW, BN = 16 * TW, BK = 16;
  const int z = blockIdx.z;
  W += (long)z * sW; bias += (long)z * sBias; C += (long)z * sC;
  const int im = blockIdx.y, in = blockIdx.x;
  const int tid = threadIdx.x;
  const int tx = tid & 15, ty = tid >> 4;
  __shared__ __align__(16) float As[BK][BM + 4];   // transposed A tile
  __shared__ __align__(16) float Bs[BK][BN];
  float acc[TW][TW] = {};
  const int arow = im * BM;
  const int bcol = in * BN;
  for (int kt = 0; kt < K; kt += BK) {
    #pragma unroll
    for (int it = 0; it < TW / 4; ++it) {
      int idx = tid + it * 256;
      int row = idx >> 2;
      int kl = (idx & 3) << 2;
      const float4 a4 = *(const float4*)(A + (long)(arow + row) * K + kt + kl);
      As[kl + 0][row] = a4.x; As[kl + 1][row] = a4.y;
      As[kl + 2][row] = a4.z; As[kl + 3][row] = a4.w;
    }
    #pragma unroll
    for (int it = 0; it < TW / 4; ++it) {
      int idx = tid + it * 256;
      int r = idx / (BN / 4);
      int c4 = (idx % (BN / 4)) << 2;
      *(float4*)(&Bs[r][c4]) = *(const float4*)(W + (long)(kt + r) * N + bcol + c4);
    }
    __syncthreads();
    #pragma unroll
    for (int kk = 0; kk < BK; ++kk) {
      float a[TW], b[TW];
      #pragma unroll
      for (int q = 0; q < TW / 4; ++q) *(float4*)&a[q * 4] = *(const float4*)&As[kk][ty * TW + q * 4];
      #pragma unroll
      for (int q = 0; q < TW / 4; ++q) *(float4*)&b[q * 4] = *(const float4*)&Bs[kk][tx * TW + q * 4];
      #pragma unroll
      for (int i2 = 0; i2 < TW; ++i2)
        #pragma unroll
        for (int j2 = 0; j2 < TW; ++j2)
          acc[i2][j2] = fmaf(a[i2], b[j2], acc[i2][j2]);
    }
    __syncthreads();
  }
  #pragma unroll
  for (int i2 = 0; i2 < TW; ++i2) {
    int row = arow + ty * TW + i2;
    #pragma unroll
    for (int j2 = 0; j2 < TW; ++j2) {
      int col = bcol + tx * TW + j2;
      float v = acc[i2][j2] + bias[col];
      if (MODE == 1) v += resid[(long)row * N + col];
      if (MODE == 2) v = 0.5f * v * (1.0f + erff(v * 0.70710678118654752f));
      C[(long)row * N + col] = v;
    }
  }
}

// ---------------------------------------------------------------------------
// scores[b,h,i,j] = (sum_d q[b,i,h,d]*k[b,j,h,d]) * 0.125 + mask[b,j]
// grid (4 ntile, 4 mtile, B*NH), 64x64 tiles, K=64
// ---------------------------------------------------------------------------
__global__ __launch_bounds__(256)
void attn_scores(const float* __restrict__ q, const float* __restrict__ k,
                 const float* __restrict__ mask, float* __restrict__ sc)
{
  const int z = blockIdx.z;
  const int b = z / NHq, hh = z % NHq;
  const long base = (long)b * Sq * Hq + hh * 64;
  const int im = blockIdx.y, in = blockIdx.x;
  const int tid = threadIdx.x;
  const int tx = tid & 15, ty = tid >> 4;
  __shared__ __align__(16) float Qs[16][68];
  __shared__ __align__(16) float Ks[16][68];
  float acc[4][4] = {};
  const int row = tid >> 2;
  const int kl = (tid & 3) << 2;
  for (int kt = 0; kt < 64; kt += 16) {
    float4 a4 = *(const float4*)(q + base + (long)(im * 64 + row) * Hq + kt + kl);
    Qs[kl + 0][row] = a4.x; Qs[kl + 1][row] = a4.y; Qs[kl + 2][row] = a4.z; Qs[kl + 3][row] = a4.w;
    float4 b4 = *(const float4*)(k + base + (long)(in * 64 + row) * Hq + kt + kl);
    Ks[kl + 0][row] = b4.x; Ks[kl + 1][row] = b4.y; Ks[kl + 2][row] = b4.z; Ks[kl + 3][row] = b4.w;
    __syncthreads();
    #pragma unroll
    for (int kk = 0; kk < 16; ++kk) {
      float a[4], bb[4];
      *(float4*)a = *(const float4*)&Qs[kk][ty * 4];
      *(float4*)bb = *(const float4*)&Ks[kk][tx * 4];
      #pragma unroll
      for (int i2 = 0; i2 < 4; ++i2)
        #pragma unroll
        for (int j2 = 0; j2 < 4; ++j2)
          acc[i2][j2] = fmaf(a[i2], bb[j2], acc[i2][j2]);
    }
    __syncthreads();
  }
  #pragma unroll
  for (int i2 = 0; i2 < 4; ++i2) {
    int ig = im * 64 + ty * 4 + i2;
    #pragma unroll
    for (int j2 = 0; j2 < 4; ++j2) {
      int jg = in * 64 + tx * 4 + j2;
      sc[(long)z * (Sq * Sq) + (long)ig * Sq + jg] = acc[i2][j2] * 0.125f + mask[b * Sq + jg];
    }
  }
}

// one wave per row of 256
__global__ __launch_bounds__(256)
void softmax256(float* __restrict__ sc)
{
  const int wid = threadIdx.x >> 6, lane = threadIdx.x & 63;
  const long row = (long)blockIdx.x * 4 + wid;
  float* p = sc + row * Sq;
  float v[4];
  float m = -1e30f;
  #pragma unroll
  for (int t = 0; t < 4; ++t) { v[t] = p[lane + t * 64]; m = fmaxf(m, v[t]); }
  #pragma unroll
  for (int off = 32; off >= 1; off >>= 1) m = fmaxf(m, __shfl_xor(m, off));
  float s = 0.0f;
  #pragma unroll
  for (int t = 0; t < 4; ++t) { v[t] = expf(v[t] - m); s += v[t]; }
  #pragma unroll
  for (int off = 32; off >= 1; off >>= 1) s += __shfl_xor(s, off);
  #pragma unroll
  for (int t = 0; t < 4; ++t) p[lane + t * 64] = v[t] / s;
}

// ctx[b,i,h,d] = sum_j P[b,h,i,j] * v[b,j,h,d]; grid (1, 4 mtile, B*NH)
__global__ __launch_bounds__(256)
void attn_ctx(const float* __restrict__ sc, const float* __restrict__ vv,
              float* __restrict__ ctx)
{
  const int z = blockIdx.z;
  const int b = z / NHq, hh = z % NHq;
  const float* P = sc + (long)z * (Sq * Sq);
  const float* V = vv + (long)b * Sq * Hq + hh * 64;
  float* O = ctx + (long)b * Sq * Hq + hh * 64;
  const int im = blockIdx.y;
  const int tid = threadIdx.x;
  const int tx = tid & 15, ty = tid >> 4;
  __shared__ __align__(16) float Ps[16][68];
  __shared__ __align__(16) float Vs[16][64];
  float acc[4][4] = {};
  const int row = tid >> 2;
  const int kl = (tid & 3) << 2;
  const int vr = tid >> 4, vc = (tid & 15) << 2;
  for (int kt = 0; kt < Sq; kt += 16) {
    float4 a4 = *(const float4*)(P + (long)(im * 64 + row) * Sq + kt + kl);
    Ps[kl + 0][row] = a4.x; Ps[kl + 1][row] = a4.y; Ps[kl + 2][row] = a4.z; Ps[kl + 3][row] = a4.w;
    *(float4*)&Vs[vr][vc] = *(const float4*)(V + (long)(kt + vr) * Hq + vc);
    __syncthreads();
    #pragma unroll
    for (int kk = 0; kk < 16; ++kk) {
      float a[4], bb[4];
      *(float4*)a = *(const float4*)&Ps[kk][ty * 4];
      *(float4*)bb = *(const float4*)&Vs[kk][tx * 4];
      #pragma unroll
      for (int i2 = 0; i2 < 4; ++i2)
        #pragma unroll
        for (int j2 = 0; j2 < 4; ++j2)
          acc[i2][j2] = fmaf(a[i2], bb[j2], acc[i2][j2]);
    }
    __syncthreads();
  }
  #pragma unroll
  for (int i2 = 0; i2 < 4; ++i2)
    #pragma unroll
    for (int j2 = 0; j2 < 4; ++j2)
      O[(long)(im * 64 + ty * 4 + i2) * Hq + tx * 4 + j2] = acc[i2][j2];
}

// LayerNorm per row of 768; block = 256 threads (3 elems each)
__global__ __launch_bounds__(256)
void ln_row(const float* __restrict__ x, float* __restrict__ y,
            const float* __restrict__ g, const float* __restrict__ bta)
{
  const long row = blockIdx.x;
  const float* xr = x + row * Hq;
  const int t = threadIdx.x;
  float a = xr[t], b = xr[t + 256], c = xr[t + 512];
  float s = a + b + c;
  float q = a * a + b * b + c * c;
  #pragma unroll
  for (int off = 32; off >= 1; off >>= 1) { s += __shfl_xor(s, off); q += __shfl_xor(q, off); }
  __shared__ float ss[4], qq[4];
  const int wid = t >> 6, lane = t & 63;
  if (lane == 0) { ss[wid] = s; qq[wid] = q; }
  __syncthreads();
  s = ss[0] + ss[1] + ss[2] + ss[3];
  q = qq[0] + qq[1] + qq[2] + qq[3];
  const float mean = s * (1.0f / 768.0f);
  const float var = q * (1.0f / 768.0f) - mean * mean;
  const float r = rsqrtf(var + 1e-12f);
  float* yr = y + row * Hq;
  yr[t]       = (a - mean) * r * g[t]       + bta[t];
  yr[t + 256] = (b - mean) * r * g[t + 256] + bta[t + 256];
  yr[t + 512] = (c - mean) * r * g[t + 512] + bta[t + 512];
}

// Router: one block per sample. Computes action probs, exit head, updates
// active/sel state, writes padded outputs. E_* pointers pre-offset for part.
__global__ __launch_bounds__(256)
void router_kernel(const float* __restrict__ h,
                   const float* __restrict__ A_pw, const float* __restrict__ A_pb,
                   const float* __restrict__ A_cw, const float* __restrict__ A_cb,
                   const float* __restrict__ E_pw, const float* __restrict__ E_pb,
                   const float* __restrict__ E_cw, const float* __restrict__ E_cb,
                   float* __restrict__ active,
                   float* __restrict__ probs_out, float* __restrict__ acts_out,
                   float* __restrict__ exit_logits, float* __restrict__ exit_part,
                   float* __restrict__ sel_code, int part)
{
  const int b = blockIdx.x, t = threadIdx.x;
  __shared__ float hrow[Hq], pooled[Hq];
  __shared__ float red[3][256];
  __shared__ float resL[3];
  for (int c = t; c < Hq; c += 256) hrow[c] = h[(long)b * Sq * Hq + c];
  __syncthreads();
  // ---- action head ----
  for (int c = t; c < Hq; c += 256) {
    float s = A_pb[c];
    for (int r = 0; r < Hq; ++r) s = fmaf(hrow[r], A_pw[(long)r * Hq + c], s);
    pooled[c] = tanhf(s);
  }
  __syncthreads();
  {
    float p0 = 0, p1 = 0, p2 = 0;
    for (int r = t; r < Hq; r += 256) {
      float p = pooled[r];
      p0 = fmaf(p, A_cw[r * 3 + 0], p0);
      p1 = fmaf(p, A_cw[r * 3 + 1], p1);
      p2 = fmaf(p, A_cw[r * 3 + 2], p2);
    }
    red[0][t] = p0; red[1][t] = p1; red[2][t] = p2;
  }
  __syncthreads();
  for (int s2 = 128; s2 > 0; s2 >>= 1) {
    if (t < s2) { red[0][t] += red[0][t + s2]; red[1][t] += red[1][t + s2]; red[2][t] += red[2][t + s2]; }
    __syncthreads();
  }
  if (t == 0) { resL[0] = red[0][0] + A_cb[0]; resL[1] = red[1][0] + A_cb[1]; resL[2] = red[2][0] + A_cb[2]; }
  __syncthreads();
  // ---- exit head ----
  for (int c = t; c < Hq; c += 256) {
    float s = E_pb[c];
    for (int r = 0; r < Hq; ++r) s = fmaf(hrow[r], E_pw[(long)r * Hq + c], s);
    pooled[c] = tanhf(s);
  }
  __syncthreads();
  {
    float p0 = 0, p1 = 0;
    for (int r = t; r < Hq; r += 256) {
      float p = pooled[r];
      p0 = fmaf(p, E_cw[r * 2 + 0], p0);
      p1 = fmaf(p, E_cw[r * 2 + 1], p1);
    }
    red[0][t] = p0; red[1][t] = p1;
  }
  __syncthreads();
  for (int s2 = 128; s2 > 0; s2 >>= 1) {
    if (t < s2) { red[0][t] += red[0][t + s2]; red[1][t] += red[1][t + s2]; }
    __syncthreads();
  }
  if (t == 0) {
    const float e0 = red[0][0] + E_cb[0], e1 = red[1][0] + E_cb[1];
    const float l0 = resL[0], l1 = resL[1], l2 = resL[2];
    int action = 0; float bv = l0;
    if (l1 > bv) { bv = l1; action = 1; }
    if (l2 > bv) { bv = l2; action = 2; }
    const float x0 = expf(l0 - bv), x1 = expf(l1 - bv), x2 = expf(l2 - bv);
    const float ssum = x0 + x1 + x2;
    const bool act = (active[b] != 0.0f);
    probs_out[b * 3 + 0] = act ? x0 / ssum : 1.0f;
    probs_out[b * 3 + 1] = act ? x1 / ssum : 1.0f;
    probs_out[b * 3 + 2] = act ? x2 / ssum : 1.0f;
    acts_out[b] = act ? (float)action : 0.0f;
    if (act && action == 0) {
      exit_logits[b * 2 + 0] = e0;
      exit_logits[b * 2 + 1] = e1;
      exit_part[b] = (float)part;
    }
    sel_code[b] = act ? (float)action : 0.0f;
    active[b] = (act && action != 0) ? 1.0f : 0.0f;
  }
}

__global__ __launch_bounds__(256)
void select_kernel(float* __restrict__ h, const float* __restrict__ base,
                   const float* __restrict__ large, const float* __restrict__ sel_code)
{
  const long e = (long)blockIdx.x * 256 + threadIdx.x;
  const int b = (int)(e / (Sq * Hq));
  const float c = sel_code[b];
  float v = h[e];
  if (c == 1.0f) v = base[e];
  else if (c == 2.0f) v = large[e];
  h[e] = v;
}

__global__ __launch_bounds__(64)
void init_kernel(float* __restrict__ active, float* __restrict__ exit_logits,
                 float* __restrict__ exit_part)
{
  const int t = threadIdx.x;
  if (t < 8) { active[t] = 1.0f; exit_part[t] = -1.0f; }
  if (t < 16) exit_logits[t] = 0.0f;
}

// ---------------------------------------------------------------------------
struct Bufs { float *q, *k, *v, *sc, *ffn, *ctx, *t0, *x1; };

static void run_layer(const float* x_in, float* x_out,
                      const float* aw, const float* ab,
                      const float* lng, const float* lnb,
                      const float* wi, const float* bi,
                      const float* wo, const float* bo,
                      const float* mask, const Bufs& w, hipStream_t stream)
{
  // QKV (batched z=3), 128x128 tiles
  gemm_nn<0, 8><<<dim3(Hq / 128, MROWS / 128, 3), 256, 0, stream>>>(
      x_in, aw, ab, nullptr, w.q, MROWS, Hq, Hq,
      (long)Hq * Hq, (long)Hq, (long)MROWS * Hq);
  attn_scores<<<dim3(4, 4, Bq * NHq), 256, 0, stream>>>(w.q, w.k, mask, w.sc);
  softmax256<<<dim3(Bq * NHq * Sq / 4), 256, 0, stream>>>(w.sc);
  attn_ctx<<<dim3(1, 4, Bq * NHq), 256, 0, stream>>>(w.sc, w.v, w.ctx);
  // O-proj + residual(x_in)
  gemm_nn<1, 4><<<dim3(Hq / 64, MROWS / 64), 256, 0, stream>>>(
      w.ctx, aw + 3L * Hq * Hq, ab + 3 * Hq, x_in, w.t0, MROWS, Hq, Hq, 0, 0, 0);
  ln_row<<<dim3(MROWS), 256, 0, stream>>>(w.t0, w.x1, lng, lnb);
  // FFN in + exact gelu
  gemm_nn<2, 8><<<dim3(FFq / 128, MROWS / 128), 256, 0, stream>>>(
      w.x1, wi, bi, nullptr, w.ffn, MROWS, FFq, Hq, 0, 0, 0);
  // FFN out + residual(x1)
  gemm_nn<1, 4><<<dim3(Hq / 64, MROWS / 64), 256, 0, stream>>>(
      w.ffn, wo, bo, w.x1, w.t0, MROWS, Hq, FFq, 0, 0, 0);
  ln_row<<<dim3(MROWS), 256, 0, stream>>>(w.t0, x_out, lng + Hq, lnb + Hq);
}

extern "C" void kernel_launch(void* const* d_in, const int* in_sizes, int n_in,
                              void* d_out, int out_size, void* d_ws, size_t ws_size,
                              hipStream_t stream)
{
  (void)in_sizes; (void)n_in; (void)out_size; (void)ws_size;
  const float* hidden = (const float*)d_in[0];
  const float* mask   = (const float*)d_in[1];
  const float* L_attn_w = (const float*)d_in[2];
  const float* L_attn_b = (const float*)d_in[3];
  const float* L_ln_g   = (const float*)d_in[4];
  const float* L_ln_b   = (const float*)d_in[5];
  const float* L_wi     = (const float*)d_in[6];
  const float* L_bi     = (const float*)d_in[7];
  const float* L_wo     = (const float*)d_in[8];
  const float* L_bo     = (const float*)d_in[9];
  const float* S_attn_w = (const float*)d_in[10];
  const float* S_attn_b = (const float*)d_in[11];
  const float* S_ln_g   = (const float*)d_in[12];
  const float* S_ln_b   = (const float*)d_in[13];
  const float* S_wi     = (const float*)d_in[14];
  const float* S_bi     = (const float*)d_in[15];
  const float* S_wo     = (const float*)d_in[16];
  const float* S_bo     = (const float*)d_in[17];
  const float* E_pw     = (const float*)d_in[18];
  const float* E_pb     = (const float*)d_in[19];
  const float* E_cw     = (const float*)d_in[20];
  const float* E_cb     = (const float*)d_in[21];
  const float* A_pw     = (const float*)d_in[22];
  const float* A_pb     = (const float*)d_in[23];
  const float* A_cw     = (const float*)d_in[24];
  const float* A_cb     = (const float*)d_in[25];

  float* out = (float*)d_out;
  float* h       = out;                 // 1,572,864
  float* active  = out + 1572864;       // 8
  float* probs   = out + 1572872;       // 144
  float* acts    = out + 1573016;       // 48
  float* exitl   = out + 1573064;       // 16
  float* exitp   = out + 1573080;       // 8

  float* ws = (float*)d_ws;
  float* sel  = ws;                      // 64 (8 used)
  float* qkv  = ws + 64;                 // 3 * BSH
  float* big  = qkv + 3L * BSH;          // SCSZ (scores / ffn shared: both 6,291,456)
  float* ctx  = big + SCSZ;              // BSH
  float* t0   = ctx + BSH;               // BSH
  float* x1   = t0 + BSH;                // BSH
  float* base = x1 + BSH;                // BSH
  float* large = base + BSH;             // BSH

  Bufs w;
  w.q = qkv; w.k = qkv + BSH; w.v = qkv + 2L * BSH;
  w.sc = big; w.ffn = big; w.ctx = ctx; w.t0 = t0; w.x1 = x1;

  hipMemcpyAsync(h, hidden, (size_t)BSH * sizeof(float),
                 hipMemcpyDeviceToDevice, stream);
  init_kernel<<<dim3(1), 64, 0, stream>>>(active, exitl, exitp);

  for (int i = 0; i < 6; ++i) {
    router_kernel<<<dim3(Bq), 256, 0, stream>>>(
        h, A_pw, A_pb, A_cw, A_cb,
        E_pw + (long)i * Hq * Hq, E_pb + i * Hq,
        E_cw + (long)i * Hq * 2, E_cb + i * 2,
        active, probs + i * 24, acts + i * 8, exitl, exitp, sel, i);
    // base = small layer i applied to h
    run_layer(h, base,
              S_attn_w + (long)i * 4 * Hq * Hq, S_attn_b + (long)i * 4 * Hq,
              S_ln_g + (long)i * 2 * Hq, S_ln_b + (long)i * 2 * Hq,
              S_wi + (long)i * Hq * FFq, S_bi + (long)i * FFq,
              S_wo + (long)i * FFq * Hq, S_bo + (long)i * Hq,
              mask, w, stream);
    // large = layers 2i, 2i+1 applied to h
    const int j0 = 2 * i, j1 = 2 * i + 1;
    run_layer(h, large,
              L_attn_w + (long)j0 * 4 * Hq * Hq, L_attn_b + (long)j0 * 4 * Hq,
              L_ln_g + (long)j0 * 2 * Hq, L_ln_b + (long)j0 * 2 * Hq,
              L_wi + (long)j0 * Hq * FFq, L_bi + (long)j0 * FFq,
              L_wo + (long)j0 * FFq * Hq, L_bo + (long)j0 * Hq,
              mask, w, stream);
    run_layer(large, large,
              L_attn_w + (long)j1 * 4 * Hq * Hq, L_attn_b + (long)j1 * 4 * Hq,
              L_ln_g + (long)j1 * 2 * Hq, L_ln_b + (long)j1 * 2 * Hq,
              L_wi + (long)j1 * Hq * FFq, L_bi + (long)j1 * FFq,
              L_wo + (long)j1 * FFq * Hq, L_bo + (long)j1 * Hq,
              mask, w, stream);
    select_kernel<<<dim3(BSH / 256), 256, 0, stream>>>(h, base, large, sel);
  }
}

// Round 2
// 5500.720 us; speedup vs baseline: 2.2214x; 2.2214x over previous
//
#include <hip/hip_runtime.h>
#include <math.h>

#define Bq 8
#define Sq 256
#define Hq 768
#define FFq 3072
#define NHq 12
#define MROWS (Bq*Sq)          /* 2048 */
#define BSH (Bq*Sq*Hq)         /* 1,572,864 floats */

typedef __attribute__((ext_vector_type(8))) short short8;
typedef __attribute__((ext_vector_type(4))) float float4v;

// ---------------------------------------------------------------------------
// bf16 split helpers
// ---------------------------------------------------------------------------
__device__ __forceinline__ unsigned short f2bf(float f) {
  unsigned u = __float_as_uint(f);
  return (unsigned short)((u + 0x7fffu + ((u >> 16) & 1u)) >> 16);
}
__device__ __forceinline__ float bf2f(unsigned short h) {
  return __uint_as_float(((unsigned)h) << 16);
}
__device__ __forceinline__ uint4 pack8(const unsigned short* s) {
  uint4 u;
  u.x = (unsigned)s[0] | ((unsigned)s[1] << 16);
  u.y = (unsigned)s[2] | ((unsigned)s[3] << 16);
  u.z = (unsigned)s[4] | ((unsigned)s[5] << 16);
  u.w = (unsigned)s[6] | ((unsigned)s[7] << 16);
  return u;
}

// Fragment-blocked bf16 plane addressing: matrix (rows R, inner dim K).
// 1KB block per (rowtile=row/16, kc=k/32); lane = (row&15) | quad<<4 holds
// 16B = 8 bf16 of k = quad*8..+7. KC = K/32. Returns BYTE offset.
__device__ __forceinline__ size_t fbaddr(int row, int col, int KC) {
  return ((((size_t)(row >> 4)) * KC + (col >> 5)) << 10)
       + ((size_t)(((row & 15) | (((col >> 3) & 3) << 4))) << 4)
       + (size_t)((col & 7) << 1);
}

__device__ __forceinline__ void dma16(const void* g, void* l) {
  __builtin_amdgcn_global_load_lds(
      (const __attribute__((address_space(1))) unsigned int*)g,
      (__attribute__((address_space(3))) unsigned int*)l, 16, 0, 0);
}

// ---------------------------------------------------------------------------
// Weight prep: W fp32 [K][N] row-major -> FB16 planes over (rows=N, K) i.e.
// B-operand (k-major per column). grid (N/64, K/32, z-mats).
// ---------------------------------------------------------------------------
__global__ __launch_bounds__(256)
void prep_w(const float* __restrict__ Wg, char* __restrict__ planes,
            int K, int N, long sInElem, long sOutBytes)
{
  const int z = blockIdx.z;
  const float* W = Wg + (size_t)z * sInElem;
  char* hi = planes + (size_t)z * sOutBytes;
  char* lo = hi + (size_t)K * N * 2;
  const int n0 = blockIdx.x * 64, k0 = blockIdx.y * 32;
  const int t = threadIdx.x;
  __shared__ __align__(16) float Ws[32][68];
  {
    int rowk = t >> 3, cc = (t & 7) * 8;
    const float* src = W + (size_t)(k0 + rowk) * N + n0 + cc;
    float4 A4 = ((const float4*)src)[0];
    float4 B4 = ((const float4*)src)[1];
    *(float4*)&Ws[rowk][cc] = A4;
    *(float4*)&Ws[rowk][cc + 4] = B4;
  }
  __syncthreads();
  const int nl = (t & 15) | ((t >> 6) << 4);   // 0..63
  const int k8 = (t >> 4) & 3;
  unsigned short hs[8], ls[8];
  #pragma unroll
  for (int j = 0; j < 8; ++j) {
    float v = Ws[k8 * 8 + j][nl];
    unsigned short h = f2bf(v);
    hs[j] = h;
    ls[j] = f2bf(v - bf2f(h));
  }
  const int ng = n0 + nl;
  size_t off = (((size_t)(ng >> 4)) * (K >> 5) + (k0 >> 5)) * 1024
             + (size_t)(((ng & 15) | (k8 << 4)) << 4);
  *(uint4*)(hi + off) = pack8(hs);
  *(uint4*)(lo + off) = pack8(ls);
}

// ---------------------------------------------------------------------------
// Split-bf16 MFMA GEMM. A planes FB16 (M,K); W planes FB16 (N,K) (pre-T).
// MODE 0: C=acc+bias (fp32, z-batched)   1: +resid fp32
//      2: gelu -> planes only            3: +resid from planes (hi+lo)
// MT=2 -> 64x64 tile, MT=4 -> 128x128. 256 threads, 4 waves in 2x2.
// ---------------------------------------------------------------------------
template<int MT, int MODE>
__global__ __launch_bounds__(256)
void gemm_fb(const char* __restrict__ Ahi, const char* __restrict__ Alo,
             const char* __restrict__ Wpl, long sW,
             const float* __restrict__ bias, long sBias,
             const float* __restrict__ residF,
             const char* __restrict__ Rhi, const char* __restrict__ Rlo,
             float* __restrict__ C, long sC,
             char* __restrict__ Phi, char* __restrict__ Plo,
             int N, int K)
{
  constexpr int TILE = MT * 32;
  constexpr int NB = 2 * MT;                   // 1KB blocks per plane
  __shared__ __align__(16) char lds[TILE * 256];  // Ahi|Alo|Bhi|Blo
  const int z = blockIdx.z;
  const char* whi = Wpl + (size_t)z * sW;
  const char* wlo = whi + (size_t)K * N * 2;
  const float* bz = bias + (size_t)z * sBias;
  float* Cz = (MODE == 2) ? nullptr : (C + (size_t)z * sC);
  const int tid = threadIdx.x, lane = tid & 63, wv = tid >> 6;
  const int wm = wv >> 1, wn = wv & 1;
  const int arow0 = blockIdx.y * TILE, bcol0 = blockIdx.x * TILE;
  const int KC = K >> 5;
  const char* bases[4] = {Ahi, Alo, whi, wlo};
  const char* wbase = bases[wv];
  const int rt0 = ((wv < 2) ? arow0 : bcol0) >> 4;
  float4v acc[MT][MT];
  #pragma unroll
  for (int i = 0; i < MT; ++i)
    #pragma unroll
    for (int j = 0; j < MT; ++j)
      acc[i][j] = (float4v){0.f, 0.f, 0.f, 0.f};

  for (int kc = 0; kc < KC; ++kc) {
    #pragma unroll
    for (int j = 0; j < NB; ++j) {
      size_t g = ((((size_t)(rt0 + j)) * KC + kc) << 10) + (size_t)lane * 16;
      dma16(wbase + g, lds + (wv * NB + j) * 1024);
    }
    __syncthreads();
    short8 bh[MT], bl[MT];
    #pragma unroll
    for (int nt = 0; nt < MT; ++nt) {
      bh[nt] = *(const short8*)(lds + (4 * MT + wn * MT + nt) * 1024 + lane * 16);
      bl[nt] = *(const short8*)(lds + (6 * MT + wn * MT + nt) * 1024 + lane * 16);
    }
    #pragma unroll
    for (int mt = 0; mt < MT; ++mt) {
      short8 ah = *(const short8*)(lds + (wm * MT + mt) * 1024 + lane * 16);
      short8 al = *(const short8*)(lds + (2 * MT + wm * MT + mt) * 1024 + lane * 16);
      #pragma unroll
      for (int nt = 0; nt < MT; ++nt) {
        acc[mt][nt] = __builtin_amdgcn_mfma_f32_16x16x32_bf16(ah, bh[nt], acc[mt][nt], 0, 0, 0);
        acc[mt][nt] = __builtin_amdgcn_mfma_f32_16x16x32_bf16(ah, bl[nt], acc[mt][nt], 0, 0, 0);
        acc[mt][nt] = __builtin_amdgcn_mfma_f32_16x16x32_bf16(al, bh[nt], acc[mt][nt], 0, 0, 0);
      }
    }
    __syncthreads();
  }
  // epilogue: C layout col=lane&15, row=quad*4+reg
  const int qd = lane >> 4, cI = lane & 15;
  const int KCo = N >> 5;
  #pragma unroll
  for (int mt = 0; mt < MT; ++mt) {
    #pragma unroll
    for (int nt = 0; nt < MT; ++nt) {
      int row0 = arow0 + (wm * MT + mt) * 16 + qd * 4;
      int col  = bcol0 + (wn * MT + nt) * 16 + cI;
      float bv = bz[col];
      #pragma unroll
      for (int r = 0; r < 4; ++r) {
        int row = row0 + r;
        float v = acc[mt][nt][r] + bv;
        if (MODE == 1) v += residF[(size_t)row * N + col];
        if (MODE == 3) {
          size_t ra = fbaddr(row, col, KCo);
          v += bf2f(*(const unsigned short*)(Rhi + ra))
             + bf2f(*(const unsigned short*)(Rlo + ra));
        }
        if (MODE == 2) {
          v = 0.5f * v * (1.0f + erff(v * 0.70710678118654752f));
          unsigned short hb = f2bf(v);
          unsigned short lb = f2bf(v - bf2f(hb));
          size_t pa = fbaddr(row, col, KCo);
          *(unsigned short*)(Phi + pa) = hb;
          *(unsigned short*)(Plo + pa) = lb;
        } else {
          Cz[(size_t)row * N + col] = v;
        }
      }
    }
  }
}

// ---------------------------------------------------------------------------
// Attention (fp32 VALU, as round 0) — scores, softmax, ctx(->planes)
// ---------------------------------------------------------------------------
__global__ __launch_bounds__(256)
void attn_scores(const float* __restrict__ q, const float* __restrict__ k,
                 const float* __restrict__ mask, float* __restrict__ sc)
{
  const int z = blockIdx.z;
  const int b = z / NHq, hh = z % NHq;
  const long base = (long)b * Sq * Hq + hh * 64;
  const int im = blockIdx.y, in = blockIdx.x;
  const int tid = threadIdx.x;
  const int tx = tid & 15, ty = tid >> 4;
  __shared__ __align__(16) float Qs[16][68];
  __shared__ __align__(16) float Ks[16][68];
  float acc[4][4] = {};
  const int row = tid >> 2;
  const int kl = (tid & 3) << 2;
  for (int kt = 0; kt < 64; kt += 16) {
    float4 a4 = *(const float4*)(q + base + (long)(im * 64 + row) * Hq + kt + kl);
    Qs[kl + 0][row] = a4.x; Qs[kl + 1][row] = a4.y; Qs[kl + 2][row] = a4.z; Qs[kl + 3][row] = a4.w;
    float4 b4 = *(const float4*)(k + base + (long)(in * 64 + row) * Hq + kt + kl);
    Ks[kl + 0][row] = b4.x; Ks[kl + 1][row] = b4.y; Ks[kl + 2][row] = b4.z; Ks[kl + 3][row] = b4.w;
    __syncthreads();
    #pragma unroll
    for (int kk = 0; kk < 16; ++kk) {
      float a[4], bb[4];
      *(float4*)a = *(const float4*)&Qs[kk][ty * 4];
      *(float4*)bb = *(const float4*)&Ks[kk][tx * 4];
      #pragma unroll
      for (int i2 = 0; i2 < 4; ++i2)
        #pragma unroll
        for (int j2 = 0; j2 < 4; ++j2)
          acc[i2][j2] = fmaf(a[i2], bb[j2], acc[i2][j2]);
    }
    __syncthreads();
  }
  #pragma unroll
  for (int i2 = 0; i2 < 4; ++i2) {
    int ig = im * 64 + ty * 4 + i2;
    #pragma unroll
    for (int j2 = 0; j2 < 4; ++j2) {
      int jg = in * 64 + tx * 4 + j2;
      sc[(long)z * (Sq * Sq) + (long)ig * Sq + jg] = acc[i2][j2] * 0.125f + mask[b * Sq + jg];
    }
  }
}

__global__ __launch_bounds__(256)
void softmax256(float* __restrict__ sc)
{
  const int wid = threadIdx.x >> 6, lane = threadIdx.x & 63;
  const long row = (long)blockIdx.x * 4 + wid;
  float* p = sc + row * Sq;
  float v[4];
  float m = -1e30f;
  #pragma unroll
  for (int t = 0; t < 4; ++t) { v[t] = p[lane + t * 64]; m = fmaxf(m, v[t]); }
  #pragma unroll
  for (int off = 32; off >= 1; off >>= 1) m = fmaxf(m, __shfl_xor(m, off));
  float s = 0.0f;
  #pragma unroll
  for (int t = 0; t < 4; ++t) { v[t] = expf(v[t] - m); s += v[t]; }
  #pragma unroll
  for (int off = 32; off >= 1; off >>= 1) s += __shfl_xor(s, off);
  #pragma unroll
  for (int t = 0; t < 4; ++t) p[lane + t * 64] = v[t] / s;
}

// ctx -> FB16 planes (over M=2048 rows, K=768)
__global__ __launch_bounds__(256)
void attn_ctx(const float* __restrict__ sc, const float* __restrict__ vv,
              char* __restrict__ Phi, char* __restrict__ Plo)
{
  const int z = blockIdx.z;
  const int b = z / NHq, hh = z % NHq;
  const float* P = sc + (long)z * (Sq * Sq);
  const float* V = vv + (long)b * Sq * Hq + hh * 64;
  const int im = blockIdx.y;
  const int tid = threadIdx.x;
  const int tx = tid & 15, ty = tid >> 4;
  __shared__ __align__(16) float Ps[16][68];
  __shared__ __align__(16) float Vs[16][64];
  float acc[4][4] = {};
  const int row = tid >> 2;
  const int kl = (tid & 3) << 2;
  const int vr = tid >> 4, vc = (tid & 15) << 2;
  for (int kt = 0; kt < Sq; kt += 16) {
    float4 a4 = *(const float4*)(P + (long)(im * 64 + row) * Sq + kt + kl);
    Ps[kl + 0][row] = a4.x; Ps[kl + 1][row] = a4.y; Ps[kl + 2][row] = a4.z; Ps[kl + 3][row] = a4.w;
    *(float4*)&Vs[vr][vc] = *(const float4*)(V + (long)(kt + vr) * Hq + vc);
    __syncthreads();
    #pragma unroll
    for (int kk = 0; kk < 16; ++kk) {
      float a[4], bb[4];
      *(float4*)a = *(const float4*)&Ps[kk][ty * 4];
      *(float4*)bb = *(const float4*)&Vs[kk][tx * 4];
      #pragma unroll
      for (int i2 = 0; i2 < 4; ++i2)
        #pragma unroll
        for (int j2 = 0; j2 < 4; ++j2)
          acc[i2][j2] = fmaf(a[i2], bb[j2], acc[i2][j2]);
    }
    __syncthreads();
  }
  const int c0 = hh * 64 + tx * 4;
  #pragma unroll
  for (int i2 = 0; i2 < 4; ++i2) {
    int grow = b * 256 + im * 64 + ty * 4 + i2;
    unsigned short h[4], l[4];
    #pragma unroll
    for (int j2 = 0; j2 < 4; ++j2) {
      float x = acc[i2][j2];
      h[j2] = f2bf(x);
      l[j2] = f2bf(x - bf2f(h[j2]));
    }
    size_t pa = fbaddr(grow, c0, 24);
    uint2 uh; uh.x = (unsigned)h[0] | ((unsigned)h[1] << 16); uh.y = (unsigned)h[2] | ((unsigned)h[3] << 16);
    uint2 ul; ul.x = (unsigned)l[0] | ((unsigned)l[1] << 16); ul.y = (unsigned)l[2] | ((unsigned)l[3] << 16);
    *(uint2*)(Phi + pa) = uh;
    *(uint2*)(Plo + pa) = ul;
  }
}

// ---------------------------------------------------------------------------
// LayerNorm (row of 768) -> FB16 planes
// ---------------------------------------------------------------------------
__global__ __launch_bounds__(256)
void ln_fb(const float* __restrict__ x, char* __restrict__ yh, char* __restrict__ yl,
           const float* __restrict__ g, const float* __restrict__ bta)
{
  const int row = blockIdx.x, t = threadIdx.x;
  const float* xr = x + (size_t)row * Hq;
  __shared__ float xs[Hq];
  __shared__ float ss[4], qq[4];
  float a = xr[t], b = xr[t + 256], c = xr[t + 512];
  xs[t] = a; xs[t + 256] = b; xs[t + 512] = c;
  float s = a + b + c;
  float q2 = a * a + b * b + c * c;
  #pragma unroll
  for (int off = 32; off >= 1; off >>= 1) { s += __shfl_xor(s, off); q2 += __shfl_xor(q2, off); }
  const int wid = t >> 6, lane = t & 63;
  if (lane == 0) { ss[wid] = s; qq[wid] = q2; }
  __syncthreads();
  s = ss[0] + ss[1] + ss[2] + ss[3];
  q2 = qq[0] + qq[1] + qq[2] + qq[3];
  const float mean = s * (1.0f / 768.0f);
  const float var = q2 * (1.0f / 768.0f) - mean * mean;
  const float r = rsqrtf(var + 1e-12f);
  if (t < 96) {
    const int c0 = t * 8;
    unsigned short hs[8], ls[8];
    #pragma unroll
    for (int j = 0; j < 8; ++j) {
      float y = (xs[c0 + j] - mean) * r * g[c0 + j] + bta[c0 + j];
      hs[j] = f2bf(y);
      ls[j] = f2bf(y - bf2f(hs[j]));
    }
    size_t pa = fbaddr(row, c0, 24);
    *(uint4*)(yh + pa) = pack8(hs);
    *(uint4*)(yl + pa) = pack8(ls);
  }
}

// ---------------------------------------------------------------------------
// h0: copy fp32 + emit planes. grid 768 x 256.
// ---------------------------------------------------------------------------
__global__ __launch_bounds__(256)
void h0split(const float* __restrict__ src, float* __restrict__ hout,
             char* __restrict__ hh, char* __restrict__ hl)
{
  const int idx = blockIdx.x * 256 + threadIdx.x;
  const int row = idx / 96, c0 = (idx % 96) * 8;
  const float* p = src + (size_t)row * Hq + c0;
  float v[8];
  *(float4*)&v[0] = ((const float4*)p)[0];
  *(float4*)&v[4] = ((const float4*)p)[1];
  float* o = hout + (size_t)row * Hq + c0;
  ((float4*)o)[0] = *(float4*)&v[0];
  ((float4*)o)[1] = *(float4*)&v[4];
  unsigned short hs[8], ls[8];
  #pragma unroll
  for (int j = 0; j < 8; ++j) { hs[j] = f2bf(v[j]); ls[j] = f2bf(v[j] - bf2f(hs[j])); }
  size_t pa = fbaddr(row, c0, 24);
  *(uint4*)(hh + pa) = pack8(hs);
  *(uint4*)(hl + pa) = pack8(ls);
}

// ---------------------------------------------------------------------------
// Select: h = (code==1)?base:(code==2)?large:h ; refresh fp32 + planes
// ---------------------------------------------------------------------------
__global__ __launch_bounds__(256)
void select_fb(float* __restrict__ hout, char* __restrict__ hh, char* __restrict__ hl,
               const char* __restrict__ bh, const char* __restrict__ bl,
               const char* __restrict__ gh, const char* __restrict__ gl,
               const float* __restrict__ sel)
{
  const int idx = blockIdx.x * 256 + threadIdx.x;
  const int row = idx / 96, c0 = (idx % 96) * 8;
  const int b = row >> 8;
  const float code = sel[b];
  const size_t pa = fbaddr(row, c0, 24);
  float v[8];
  if (code == 1.0f || code == 2.0f) {
    const char* sh = (code == 1.0f) ? bh : gh;
    const char* sl = (code == 1.0f) ? bl : gl;
    uint4 H = *(const uint4*)(sh + pa);
    uint4 L = *(const uint4*)(sl + pa);
    const unsigned* hw = (const unsigned*)&H;
    const unsigned* lw = (const unsigned*)&L;
    #pragma unroll
    for (int j = 0; j < 8; ++j) {
      unsigned short hb = (unsigned short)(hw[j >> 1] >> ((j & 1) * 16));
      unsigned short lb = (unsigned short)(lw[j >> 1] >> ((j & 1) * 16));
      v[j] = bf2f(hb) + bf2f(lb);
    }
  } else {
    const float* p = hout + (size_t)row * Hq + c0;
    *(float4*)&v[0] = ((const float4*)p)[0];
    *(float4*)&v[4] = ((const float4*)p)[1];
  }
  float* o = hout + (size_t)row * Hq + c0;
  ((float4*)o)[0] = *(float4*)&v[0];
  ((float4*)o)[1] = *(float4*)&v[4];
  unsigned short hs[8], ls[8];
  #pragma unroll
  for (int j = 0; j < 8; ++j) { hs[j] = f2bf(v[j]); ls[j] = f2bf(v[j] - bf2f(hs[j])); }
  *(uint4*)(hh + pa) = pack8(hs);
  *(uint4*)(hl + pa) = pack8(ls);
}

// ---------------------------------------------------------------------------
// Router (unchanged from round 0, reads fp32 h)
// ---------------------------------------------------------------------------
__global__ __launch_bounds__(256)
void router_kernel(const float* __restrict__ h,
                   const float* __restrict__ A_pw, const float* __restrict__ A_pb,
                   const float* __restrict__ A_cw, const float* __restrict__ A_cb,
                   const float* __restrict__ E_pw, const float* __restrict__ E_pb,
                   const float* __restrict__ E_cw, const float* __restrict__ E_cb,
                   float* __restrict__ active,
                   float* __restrict__ probs_out, float* __restrict__ acts_out,
                   float* __restrict__ exit_logits, float* __restrict__ exit_part,
                   float* __restrict__ sel_code, int part)
{
  const int b = blockIdx.x, t = threadIdx.x;
  __shared__ float hrow[Hq], pooled[Hq];
  __shared__ float red[3][256];
  __shared__ float resL[3];
  for (int c = t; c < Hq; c += 256) hrow[c] = h[(long)b * Sq * Hq + c];
  __syncthreads();
  for (int c = t; c < Hq; c += 256) {
    float s = A_pb[c];
    for (int r = 0; r < Hq; ++r) s = fmaf(hrow[r], A_pw[(long)r * Hq + c], s);
    pooled[c] = tanhf(s);
  }
  __syncthreads();
  {
    float p0 = 0, p1 = 0, p2 = 0;
    for (int r = t; r < Hq; r += 256) {
      float p = pooled[r];
      p0 = fmaf(p, A_cw[r * 3 + 0], p0);
      p1 = fmaf(p, A_cw[r * 3 + 1], p1);
      p2 = fmaf(p, A_cw[r * 3 + 2], p2);
    }
    red[0][t] = p0; red[1][t] = p1; red[2][t] = p2;
  }
  __syncthreads();
  for (int s2 = 128; s2 > 0; s2 >>= 1) {
    if (t < s2) { red[0][t] += red[0][t + s2]; red[1][t] += red[1][t + s2]; red[2][t] += red[2][t + s2]; }
    __syncthreads();
  }
  if (t == 0) { resL[0] = red[0][0] + A_cb[0]; resL[1] = red[1][0] + A_cb[1]; resL[2] = red[2][0] + A_cb[2]; }
  __syncthreads();
  for (int c = t; c < Hq; c += 256) {
    float s = E_pb[c];
    for (int r = 0; r < Hq; ++r) s = fmaf(hrow[r], E_pw[(long)r * Hq + c], s);
    pooled[c] = tanhf(s);
  }
  __syncthreads();
  {
    float p0 = 0, p1 = 0;
    for (int r = t; r < Hq; r += 256) {
      float p = pooled[r];
      p0 = fmaf(p, E_cw[r * 2 + 0], p0);
      p1 = fmaf(p, E_cw[r * 2 + 1], p1);
    }
    red[0][t] = p0; red[1][t] = p1;
  }
  __syncthreads();
  for (int s2 = 128; s2 > 0; s2 >>= 1) {
    if (t < s2) { red[0][t] += red[0][t + s2]; red[1][t] += red[1][t + s2]; }
    __syncthreads();
  }
  if (t == 0) {
    const float e0 = red[0][0] + E_cb[0], e1 = red[1][0] + E_cb[1];
    const float l0 = resL[0], l1 = resL[1], l2 = resL[2];
    int action = 0; float bv = l0;
    if (l1 > bv) { bv = l1; action = 1; }
    if (l2 > bv) { bv = l2; action = 2; }
    const float x0 = expf(l0 - bv), x1 = expf(l1 - bv), x2 = expf(l2 - bv);
    const float ssum = x0 + x1 + x2;
    const bool act = (active[b] != 0.0f);
    probs_out[b * 3 + 0] = act ? x0 / ssum : 1.0f;
    probs_out[b * 3 + 1] = act ? x1 / ssum : 1.0f;
    probs_out[b * 3 + 2] = act ? x2 / ssum : 1.0f;
    acts_out[b] = act ? (float)action : 0.0f;
    if (act && action == 0) {
      exit_logits[b * 2 + 0] = e0;
      exit_logits[b * 2 + 1] = e1;
      exit_part[b] = (float)part;
    }
    sel_code[b] = act ? (float)action : 0.0f;
    active[b] = (act && action != 0) ? 1.0f : 0.0f;
  }
}

__global__ __launch_bounds__(64)
void init_kernel(float* __restrict__ active, float* __restrict__ exit_logits,
                 float* __restrict__ exit_part)
{
  const int t = threadIdx.x;
  if (t < 8) { active[t] = 1.0f; exit_part[t] = -1.0f; }
  if (t < 16) exit_logits[t] = 0.0f;
}

// ---------------------------------------------------------------------------
struct WS {
  float* sel;
  char* wjit;                       // 9,437,184 B (one matrix / 4 attn mats)
  float* q; float* k; float* v;     // fp32 scratch; q reused as x1 planes,
                                    // k reused as ctx planes then FFN2-out fp32
  float* big;                       // scores fp32 -> O-out fp32 -> ffn planes
  const float* mask;
  float* hout;                      // fp32 h in d_out
};

#define MATATTN 2359296L            /* bytes: 768*768*4 (one plane pair) */
#define ACTPL   3145728L            /* bytes per activation plane (2048*768*2) */

static void run_layer_fb(const char* xhi, const char* xlo,
                         const float* residF, const char* rOhi, const char* rOlo,
                         char* outhi, char* outlo,
                         const float* aw, const float* ab,
                         const float* lng, const float* lnb,
                         const float* wi, const float* bi,
                         const float* wo, const float* bo,
                         const WS& W, hipStream_t s)
{
  // attention weights -> planes (Wq,Wk,Wv,Wo)
  prep_w<<<dim3(12, 24, 4), 256, 0, s>>>(aw, W.wjit, 768, 768, 589824L, MATATTN);
  // QKV (z=3)
  gemm_fb<2, 0><<<dim3(12, 32, 3), 256, 0, s>>>(
      xhi, xlo, W.wjit, MATATTN, ab, 768, nullptr, nullptr, nullptr,
      W.q, (long)BSH, nullptr, nullptr, 768, 768);
  attn_scores<<<dim3(4, 4, 96), 256, 0, s>>>(W.q, W.k, W.mask, W.big);
  softmax256<<<dim3(96 * 256 / 4), 256, 0, s>>>(W.big);
  char* cph = (char*)W.k;             // ctx planes overwrite k (dead)
  char* cpl = cph + ACTPL;
  attn_ctx<<<dim3(1, 4, 96), 256, 0, s>>>(W.big, W.v, cph, cpl);
  float* t0 = W.big;                  // O out fp32 (scores dead)
  if (residF) {
    gemm_fb<2, 1><<<dim3(12, 32), 256, 0, s>>>(
        cph, cpl, W.wjit + 3 * MATATTN, 0, ab + 3 * 768, 0, residF, nullptr, nullptr,
        t0, 0, nullptr, nullptr, 768, 768);
  } else {
    gemm_fb<2, 3><<<dim3(12, 32), 256, 0, s>>>(
        cph, cpl, W.wjit + 3 * MATATTN, 0, ab + 3 * 768, 0, nullptr, rOhi, rOlo,
        t0, 0, nullptr, nullptr, 768, 768);
  }
  char* x1h = (char*)W.q;             // x1 planes overwrite q (dead)
  char* x1l = x1h + ACTPL;
  ln_fb<<<MROWS, 256, 0, s>>>(t0, x1h, x1l, lng, lnb);
  // FFN1 (gelu -> planes in big; t0 dead after ln)
  prep_w<<<dim3(48, 24, 1), 256, 0, s>>>(wi, W.wjit, 768, 3072, 0, 0);
  char* fph = (char*)W.big;
  char* fpl = fph + 2048L * 3072 * 2;
  gemm_fb<4, 2><<<dim3(24, 16), 256, 0, s>>>(
      x1h, x1l, W.wjit, 0, bi, 0, nullptr, nullptr, nullptr,
      nullptr, 0, fph, fpl, 3072, 768);
  // FFN2 (+resid from x1 planes) -> fp32 in k region (ctx planes dead)
  prep_w<<<dim3(12, 96, 1), 256, 0, s>>>(wo, W.wjit, 3072, 768, 0, 0);
  float* t2 = W.k;
  gemm_fb<2, 3><<<dim3(12, 32), 256, 0, s>>>(
      fph, fpl, W.wjit, 0, bo, 0, nullptr, x1h, x1l,
      t2, 0, nullptr, nullptr, 768, 3072);
  ln_fb<<<MROWS, 256, 0, s>>>(t2, outhi, outlo, lng + 768, lnb + 768);
}

extern "C" void kernel_launch(void* const* d_in, const int* in_sizes, int n_in,
                              void* d_out, int out_size, void* d_ws, size_t ws_size,
                              hipStream_t stream)
{
  (void)in_sizes; (void)n_in; (void)out_size; (void)ws_size;
  const float* hidden   = (const float*)d_in[0];
  const float* mask     = (const float*)d_in[1];
  const float* L_attn_w = (const float*)d_in[2];
  const float* L_attn_b = (const float*)d_in[3];
  const float* L_ln_g   = (const float*)d_in[4];
  const float* L_ln_b   = (const float*)d_in[5];
  const float* L_wi     = (const float*)d_in[6];
  const float* L_bi     = (const float*)d_in[7];
  const float* L_wo     = (const float*)d_in[8];
  const float* L_bo     = (const float*)d_in[9];
  const float* S_attn_w = (const float*)d_in[10];
  const float* S_attn_b = (const float*)d_in[11];
  const float* S_ln_g   = (const float*)d_in[12];
  const float* S_ln_b   = (const float*)d_in[13];
  const float* S_wi     = (const float*)d_in[14];
  const float* S_bi     = (const float*)d_in[15];
  const float* S_wo     = (const float*)d_in[16];
  const float* S_bo     = (const float*)d_in[17];
  const float* E_pw     = (const float*)d_in[18];
  const float* E_pb     = (const float*)d_in[19];
  const float* E_cw     = (const float*)d_in[20];
  const float* E_cb     = (const float*)d_in[21];
  const float* A_pw     = (const float*)d_in[22];
  const float* A_pb     = (const float*)d_in[23];
  const float* A_cw     = (const float*)d_in[24];
  const float* A_cb     = (const float*)d_in[25];

  float* out = (float*)d_out;
  float* h      = out;
  float* active = out + 1572864;
  float* probs  = out + 1572872;
  float* acts   = out + 1573016;
  float* exitl  = out + 1573064;
  float* exitp  = out + 1573080;

  char* ws = (char*)d_ws;
  float* sel    = (float*)ws;                       // 256 B
  char* wjit    = ws + 256;                         // 9,437,184
  char* qreg    = wjit + 9437184;                   // 6,291,456
  char* kreg    = qreg + 6291456;                   // 6,291,456
  char* vreg    = kreg + 6291456;                   // 6,291,456
  char* bigc    = vreg + 6291456;                   // 25,165,824
  char* basepl  = bigc + 25165824;                  // 6,291,456
  char* largepl = basepl + 6291456;                 // 6,291,456
  char* hpl     = largepl + 6291456;                // 6,291,456  (total ~72.3 MB)

  WS W;
  W.sel = sel; W.wjit = wjit;
  W.q = (float*)qreg; W.k = (float*)kreg; W.v = (float*)vreg;
  W.big = (float*)bigc; W.mask = mask; W.hout = h;

  init_kernel<<<dim3(1), 64, 0, stream>>>(active, exitl, exitp);
  h0split<<<dim3(768), 256, 0, stream>>>(hidden, h, hpl, hpl + ACTPL);

  for (int i = 0; i < 6; ++i) {
    router_kernel<<<dim3(Bq), 256, 0, stream>>>(
        h, A_pw, A_pb, A_cw, A_cb,
        E_pw + (long)i * Hq * Hq, E_pb + i * Hq,
        E_cw + (long)i * Hq * 2, E_cb + i * 2,
        active, probs + i * 24, acts + i * 8, exitl, exitp, sel, i);
    // base = small layer i on h
    run_layer_fb(hpl, hpl + ACTPL, h, nullptr, nullptr, basepl, basepl + ACTPL,
                 S_attn_w + (long)i * 4 * Hq * Hq, S_attn_b + (long)i * 4 * Hq,
                 S_ln_g + (long)i * 2 * Hq, S_ln_b + (long)i * 2 * Hq,
                 S_wi + (long)i * Hq * FFq, S_bi + (long)i * FFq,
                 S_wo + (long)i * FFq * Hq, S_bo + (long)i * Hq, W, stream);
    // large = layers 2i, 2i+1 on h
    const int j0 = 2 * i, j1 = 2 * i + 1;
    run_layer_fb(hpl, hpl + ACTPL, h, nullptr, nullptr, largepl, largepl + ACTPL,
                 L_attn_w + (long)j0 * 4 * Hq * Hq, L_attn_b + (long)j0 * 4 * Hq,
                 L_ln_g + (long)j0 * 2 * Hq, L_ln_b + (long)j0 * 2 * Hq,
                 L_wi + (long)j0 * Hq * FFq, L_bi + (long)j0 * FFq,
                 L_wo + (long)j0 * FFq * Hq, L_bo + (long)j0 * Hq, W, stream);
    run_layer_fb(largepl, largepl + ACTPL, nullptr, largepl, largepl + ACTPL,
                 largepl, largepl + ACTPL,
                 L_attn_w + (long)j1 * 4 * Hq * Hq, L_attn_b + (long)j1 * 4 * Hq,
                 L_ln_g + (long)j1 * 2 * Hq, L_ln_b + (long)j1 * 2 * Hq,
                 L_wi + (long)j1 * Hq * FFq, L_bi + (long)j1 * FFq,
                 L_wo + (long)j1 * FFq * Hq, L_bo + (long)j1 * Hq, W, stream);
    select_fb<<<dim3(768), 256, 0, stream>>>(h, hpl, hpl + ACTPL,
                                             basepl, basepl + ACTPL,
                                             largepl, largepl + ACTPL, sel);
  }
}